// Round 7
// baseline (301.005 us; speedup 1.0000x reference)
//
#include <hip/hip_runtime.h>

#define DD 128
#define SCHUNK 4096

typedef __attribute__((ext_vector_type(8))) short short8;
typedef __attribute__((ext_vector_type(4))) float f32x4;
typedef __attribute__((ext_vector_type(2))) float f32x2;
typedef __attribute__((ext_vector_type(4))) int i32x4;
typedef __attribute__((ext_vector_type(4))) unsigned int u32x4;

__device__ __forceinline__ unsigned short f2bf(float f) {
    union { float f; unsigned int i; } c; c.f = f;
    unsigned int x = c.i;
    return (unsigned short)((x + 0x7fffu + ((x >> 16) & 1u)) >> 16);
}
__device__ __forceinline__ float bfu(unsigned short u) {
    union { unsigned int i; float f; } c; c.i = ((unsigned int)u) << 16; return c.f;
}
// unpack u32 of 2 bf16 -> {lo, hi} f32 pair (2 VALU ops, feeds v_pk_add_f32)
__device__ __forceinline__ f32x2 bf2lohi(unsigned int w) {
    union { unsigned int i; float f; } lo, hi;
    lo.i = w << 16;
    hi.i = w & 0xFFFF0000u;
    return (f32x2){lo.f, hi.f};
}
// async 16B global -> LDS (dest is wave-uniform base + lane*16)
__device__ __forceinline__ void gload_lds16(const void* g, void* l) {
    __builtin_amdgcn_global_load_lds(
        (const __attribute__((address_space(1))) unsigned int*)g,
        (__attribute__((address_space(3))) unsigned int*)l, 16, 0, 0);
}
// Index accessor robust to int32 vs int64 (little-endian, nonneg values < 2^31)
__device__ __forceinline__ int idx_at(const int* p, int e, int is64) {
    return is64 ? p[2 * e] : p[e];
}
// Per-block int64 detection: int64 => odd 32-bit words (high halves) all zero.
__device__ __forceinline__ int block_is64(const int* dst, int nE, int* s_flag) {
    if (threadIdx.x == 0) *s_flag = 0;
    __syncthreads();
    int w = 2 * (int)threadIdx.x + 1;
    if (threadIdx.x < 128 && w < nE && dst[w] != 0) atomicOr(s_flag, 1);
    __syncthreads();
    return !*s_flag;
}

// ---- prep: one kernel, roles by blockIdx:
// [0, nChunk)   : per-chunk coarse-bucket histogram (dst>>7), LDS-privatized,
//                 dense coalesced row write to chunkHist[c][b] -- NO global
//                 atomics (the old per-node atomic histogram write-through
//                 ~32B/op to HBM: 600k ops = ~18MB excess WRITE_SIZE)
// [+nConvH)     : h fp32 -> hB bf16, 8192 elems/block, 8 loads in flight
// [+48)         : 3 weights transposed+converted into Wt
// [+nEmbB)      : emb fp32 -> embB bf16
__global__ __launch_bounds__(256) void prep_k(
    const float* __restrict__ h,
    const float* __restrict__ W0, const float* __restrict__ W1,
    const float* __restrict__ W2, const float* __restrict__ emb,
    const int* __restrict__ dst,
    unsigned short* __restrict__ hB,
    unsigned short* __restrict__ embB, unsigned short* __restrict__ Wt,
    int* __restrict__ chunkHist, int nN, int nEmbEl, int nE,
    int nBuck, int nChunk) {
    int tid = threadIdx.x;
    int bid = blockIdx.x;
    if (bid < nChunk) {
        __shared__ int hist[2048];
        __shared__ int s_flag;
        int is64 = block_is64(dst, nE, &s_flag);
        for (int i = tid; i < nBuck; i += 256) hist[i] = 0;
        __syncthreads();
        int cbase = bid * SCHUNK;
        #pragma unroll
        for (int j = 0; j < SCHUNK / 256; ++j) {
            int e = cbase + j * 256 + tid;
            if (e < nE) atomicAdd(&hist[idx_at(dst, e, is64) >> 7], 1);
        }
        __syncthreads();
        for (int b = tid; b < nBuck; b += 256)
            chunkHist[bid * nBuck + b] = hist[b];
        return;
    }
    bid -= nChunk;
    int totalH = nN * DD;
    int nConvH = (totalH + 8191) / 8192;
    if (bid < nConvH) {
        int base0 = bid * 8192;
        if (base0 + 8192 <= totalH) {
            int base = base0 + tid * 8;
            f32x4 x[4][2];
            #pragma unroll
            for (int i = 0; i < 4; ++i) {
                x[i][0] = *(const f32x4*)(h + base + i * 2048);
                x[i][1] = *(const f32x4*)(h + base + i * 2048 + 4);
            }
            #pragma unroll
            for (int i = 0; i < 4; ++i) {
                short8 p;
                #pragma unroll
                for (int j = 0; j < 4; ++j) {
                    p[j]     = (short)f2bf(x[i][0][j]);
                    p[4 + j] = (short)f2bf(x[i][1][j]);
                }
                *(short8*)(hB + base + i * 2048) = p;
            }
        } else {
            #pragma unroll
            for (int i = 0; i < 4; ++i) {
                int b2 = base0 + i * 2048 + tid * 8;
                if (b2 + 8 <= totalH) {
                    f32x4 x0 = *(const f32x4*)(h + b2);
                    f32x4 x1 = *(const f32x4*)(h + b2 + 4);
                    short8 p;
                    #pragma unroll
                    for (int j = 0; j < 4; ++j) {
                        p[j]     = (short)f2bf(x0[j]);
                        p[4 + j] = (short)f2bf(x1[j]);
                    }
                    *(short8*)(hB + b2) = p;
                } else {
                    for (int j = b2; j < totalH && j < b2 + 8; ++j)
                        hB[j] = f2bf(h[j]);
                }
            }
        }
        return;
    }
    bid -= nConvH;
    if (bid < 48) {
        const float* Ws[3] = {W0, W1, W2};
        int w = bid >> 4, chunk = bid & 15;
        unsigned short* T = Wt + w * (DD * DD);
        #pragma unroll
        for (int i = 0; i < 4; ++i) {
            int t = chunk * 1024 + i * 256 + tid;
            int n = t >> 7, k = t & 127;
            T[t] = f2bf(Ws[w][k * DD + n]);
        }
        return;
    }
    bid -= 48;
    // emb role
    int base = bid * 2048 + tid * 8;
    if (base + 8 <= nEmbEl) {
        f32x4 x0 = *(const f32x4*)(emb + base);
        f32x4 x1 = *(const f32x4*)(emb + base + 4);
        short8 p;
        #pragma unroll
        for (int j = 0; j < 4; ++j) {
            p[j]     = (short)f2bf(x0[j]);
            p[4 + j] = (short)f2bf(x1[j]);
        }
        *(short8*)(embB + base) = p;
    } else {
        for (int j = base; j < nEmbEl; ++j) embB[j] = f2bf(emb[j]);
    }
}

// ---- column-scan of chunkHist (per bucket, over chunks), in place:
// chunkHist[c][b] becomes "edges of bucket b in chunks < c"; bucketTot[b] = total.
// Thread-per-bucket; loads coalesced across threads at each c.
__global__ __launch_bounds__(256) void scanB1_k(int* __restrict__ chunkHist,
                                                int* __restrict__ bucketTot,
                                                int nBuck, int nChunk) {
    int b = blockIdx.x * 256 + threadIdx.x;
    if (b >= nBuck) return;
    int tot = 0;
    for (int c = 0; c < nChunk; ++c) {
        int v = chunkHist[c * nBuck + b];
        chunkHist[c * nBuck + b] = tot;
        tot += v;
    }
    bucketTot[b] = tot;
}

// ---- exclusive scan of bucket totals -> bucketBase (one block, 2 slots/thread,
// supports nBuck <= 2048); bucketBase[nBuck] = nE.
__global__ __launch_bounds__(1024) void scanB2_k(const int* __restrict__ bucketTot,
                                                 int* __restrict__ bucketBase,
                                                 int nBuck, int nE) {
    __shared__ int s[2048];
    int t = threadIdx.x;
    int b0 = t, b1 = t + 1024;
    int v0 = (b0 < nBuck) ? bucketTot[b0] : 0;
    int v1 = (b1 < nBuck) ? bucketTot[b1] : 0;
    s[b0] = v0;
    s[b1] = v1;
    __syncthreads();
    for (int d = 1; d < 2048; d <<= 1) {
        int x0 = (b0 >= d) ? s[b0 - d] : 0;
        int x1 = (b1 >= d) ? s[b1 - d] : 0;
        __syncthreads();
        s[b0] += x0;
        s[b1] += x1;
        __syncthreads();
    }
    if (b0 < nBuck) bucketBase[b0] = s[b0] - v0;
    if (b1 < nBuck) bucketBase[b1] = s[b1] - v1;
    if (t == 0) bucketBase[nBuck] = nE;
}

// ---- sort phase 1: partition edges into coarse buckets (dst>>7); run base is
// bucketBase[b] + chunkHist[c][b] -- fully deterministic, zero global atomics.
// staged word = src | et<<17 | (dst&127)<<25.
__global__ __launch_bounds__(256) void sort1_k(
    const int* __restrict__ src, const int* __restrict__ dst,
    const int* __restrict__ et, int nE, int nBuck,
    const int* __restrict__ chunkHist, const int* __restrict__ bucketBase,
    unsigned int* __restrict__ staging) {
    __shared__ int hist[2048];
    __shared__ int rbase[2048];
    __shared__ unsigned short ranks[SCHUNK];
    __shared__ int s_flag;
    int tid = threadIdx.x;
    int is64 = block_is64(dst, nE, &s_flag);
    for (int i = tid; i < nBuck; i += 256) hist[i] = 0;
    __syncthreads();
    int c = blockIdx.x;
    int cbase = c * SCHUNK;
    #pragma unroll
    for (int j = 0; j < SCHUNK / 256; ++j) {
        int e = cbase + j * 256 + tid;
        if (e < nE) {
            int d = idx_at(dst, e, is64);
            ranks[j * 256 + tid] = (unsigned short)atomicAdd(&hist[d >> 7], 1);
        }
    }
    __syncthreads();
    for (int b = tid; b < nBuck; b += 256)
        rbase[b] = bucketBase[b] + chunkHist[c * nBuck + b];
    __syncthreads();
    #pragma unroll
    for (int j = 0; j < SCHUNK / 256; ++j) {
        int e = cbase + j * 256 + tid;
        if (e < nE) {
            int d = idx_at(dst, e, is64);
            unsigned int wd = (unsigned int)idx_at(src, e, is64) |
                              ((unsigned int)idx_at(et, e, is64) << 17) |
                              ((unsigned int)(d & 127) << 25);
            staging[rbase[d >> 7] + (int)ranks[j * 256 + tid]] = wd;
        }
    }
}

// ---- sort phase 2: one block per bucket. Counts per-node in LDS, 128-wide
// exclusive scan -> derives off[v] and deg[v] (coalesced writes; replaces the
// old global per-node histogram + 100k-scan), then scatters edges within the
// bucket's contiguous, L2-hot region.
__global__ __launch_bounds__(256) void sort2_k(
    const unsigned int* __restrict__ staging, const int* __restrict__ bucketBase,
    int nN, unsigned int* __restrict__ edges,
    int* __restrict__ off, int* __restrict__ deg) {
    __shared__ int cnt[128];
    __shared__ int sc[128];
    __shared__ int cur[128];
    int b = blockIdx.x;
    int first = b << 7;
    int tid = threadIdx.x;
    if (tid < 128) cnt[tid] = 0;
    int rStart = bucketBase[b];
    int rEnd = bucketBase[b + 1];
    __syncthreads();
    for (int i = rStart + tid; i < rEnd; i += 256)
        atomicAdd(&cnt[staging[i] >> 25], 1);
    __syncthreads();
    if (tid < 128) sc[tid] = cnt[tid];
    __syncthreads();
    for (int d = 1; d < 128; d <<= 1) {
        int x = 0;
        if (tid < 128 && tid >= d) x = sc[tid - d];
        __syncthreads();
        if (tid < 128) sc[tid] += x;
        __syncthreads();
    }
    if (tid < 128) {
        int o = rStart + sc[tid] - cnt[tid];
        cur[tid] = o;
        int v = first + tid;
        if (v < nN) { off[v] = o; deg[v] = cnt[tid]; }
    }
    __syncthreads();
    for (int i = rStart + tid; i < rEnd; i += 256) {
        unsigned int wd = staging[i];
        int p = atomicAdd(&cur[wd >> 25], 1);
        edges[p] = wd & 0x1FFFFFFu;
    }
}

// ---- CSR gather, node-per-16-lane-group: 4 nodes per wave, 16 nodes per
// block. Channels lane-local, no cross-lane reduce; f32x2 accumulators
// (v_pk_add_f32), v_cvt_pk_bf16_f32 pack epilogue.
__global__ __launch_bounds__(256) void gather_k(
    const unsigned short* __restrict__ hB, const unsigned short* __restrict__ embB,
    const unsigned int* __restrict__ edges, const int* __restrict__ off,
    const int* __restrict__ deg, const float* __restrict__ normv,
    char* __restrict__ aggP, int nN) {
    int lane = threadIdx.x & 63;
    int l16 = lane & 15;
    int v = blockIdx.x * 16 + ((threadIdx.x >> 6) << 2) + (lane >> 4);
    if (v >= nN) return;
    int b = off[v], n = deg[v];
    f32x2 a2[4] = {{0.f, 0.f}, {0.f, 0.f}, {0.f, 0.f}, {0.f, 0.f}};
    for (int m = 0; m < n; m += 2) {
        bool e1 = (m + 1) < n;
        unsigned int w0 = edges[b + m];
        unsigned int w1 = e1 ? edges[b + m + 1] : 0u;
        short8 h0 = *(const short8*)(hB + (size_t)(w0 & 0x1FFFFu) * DD + l16 * 8);
        short8 r0 = *(const short8*)(embB + (size_t)(w0 >> 17) * DD + l16 * 8);
        short8 h1, r1;
        if (e1) {
            h1 = *(const short8*)(hB + (size_t)(w1 & 0x1FFFFu) * DD + l16 * 8);
            r1 = *(const short8*)(embB + (size_t)(w1 >> 17) * DD + l16 * 8);
        }
        union { short8 s; u32x4 u; } ch0, cr0;
        ch0.s = h0; cr0.s = r0;
        #pragma unroll
        for (int k = 0; k < 4; ++k) {
            a2[k] += bf2lohi(ch0.u[k]);
            a2[k] += bf2lohi(cr0.u[k]);
        }
        if (e1) {
            union { short8 s; u32x4 u; } ch1, cr1;
            ch1.s = h1; cr1.s = r1;
            #pragma unroll
            for (int k = 0; k < 4; ++k) {
                a2[k] += bf2lohi(ch1.u[k]);
                a2[k] += bf2lohi(cr1.u[k]);
            }
        }
    }
    float nm = normv[v];
    unsigned int pk[4];
    #pragma unroll
    for (int k = 0; k < 4; ++k) {
        float x0 = a2[k][0] * nm, x1 = a2[k][1] * nm;
        asm("v_cvt_pk_bf16_f32 %0, %1, %2" : "=v"(pk[k]) : "v"(x0), "v"(x1));
    }
    i32x4 w;
    w[0] = (int)pk[0]; w[1] = (int)pk[1]; w[2] = (int)pk[2]; w[3] = (int)pk[3];
    *(i32x4*)(aggP + (size_t)v * 512 + l16 * 16) = w;
}

// ---- fused 3-GEMM + epilogue: persistent double-buffered pipeline,
// 32-node tiles, 48KB dynamic LDS -> 2 blocks/CU. Wt fragments hoisted.
// deg==0 rows patched exactly by fix_k afterwards.
__global__ __launch_bounds__(256, 2) void fused_k(
    const unsigned short* __restrict__ hB,
    const float* __restrict__ prevh,
    const float* __restrict__ bias,
    const char* __restrict__ aggP,       // = d_out: [0,256) of each 512B slot = agg bf16
    const unsigned short* __restrict__ Wt,
    float* __restrict__ out, int nN, int nTiles) {
    extern __shared__ unsigned short lds[];   // 2 * 12288 u16 = 48KB
    const int lane = threadIdx.x & 63;
    const int wv = threadIdx.x >> 6;
    const int q = lane >> 4, cl = lane & 15;
    const int ncb = wv * 32;
    const int stride = gridDim.x;

    int t = blockIdx.x;
    if (t >= nTiles) return;

    short8 bn[4][2], bl[4][2], bs[4][2];
    #pragma unroll
    for (int ks = 0; ks < 4; ++ks)
        #pragma unroll
        for (int nt = 0; nt < 2; ++nt) {
            int n = (ncb + nt * 16 + cl) * DD + ks * 32 + q * 8;
            bn[ks][nt] = *(const short8*)(Wt + n);
            bl[ks][nt] = *(const short8*)(Wt + DD * DD + n);
            bs[ks][nt] = *(const short8*)(Wt + 2 * DD * DD + n);
        }
    const float b0 = bias[ncb + cl], b1 = bias[ncb + 16 + cl];

    const int r0 = lane >> 4;
    const int c16 = lane & 15;

    {
        int node_base = t * 32;
        #pragma unroll
        for (int it = 0; it < 2; ++it) {
            int r = it * 16 + wv * 4 + r0;
            int row = node_base + r; if (row > nN - 1) row = nN - 1;
            int sw = (c16 ^ (r & 15)) << 4;
            char* bptr = (char*)lds + (it * 16 + wv * 4) * 256;
            gload_lds16(aggP + (size_t)row * 512 + sw, bptr);
            gload_lds16((const char*)hB + (size_t)row * 256 + sw, bptr + 8192);
        }
        f32x4 p0[2], p1[2];
        #pragma unroll
        for (int it = 0; it < 2; ++it) {
            int pos = it * 512 + lane * 8;
            int node = node_base + wv * 8 + (pos >> 7);
            if (node > nN - 1) node = nN - 1;
            const float* g = prevh + (size_t)node * DD + (pos & 127);
            p0[it] = *(const f32x4*)g;
            p1[it] = *(const f32x4*)(g + 4);
        }
        #pragma unroll
        for (int it = 0; it < 2; ++it) {
            int pos = it * 512 + lane * 8;
            int r = wv * 8 + (pos >> 7);
            int c = (pos & 127) >> 3;
            short8 p;
            #pragma unroll
            for (int j = 0; j < 4; ++j) {
                p[j]     = (short)f2bf(p0[it][j]);
                p[4 + j] = (short)f2bf(p1[it][j]);
            }
            *(short8*)((char*)lds + 16384 + r * 256 + ((c ^ (r & 15)) << 4)) = p;
        }
    }
    __syncthreads();

    int cur = 0;
    for (;;) {
        int node_base = t * 32;
        int tn = t + stride;
        bool more = (tn < nTiles);

        f32x4 p0[2], p1[2];
        if (more) {
            int nb2 = tn * 32;
            char* dbuf = (char*)lds + (cur ^ 1) * 24576;
            #pragma unroll
            for (int it = 0; it < 2; ++it) {
                int r = it * 16 + wv * 4 + r0;
                int row = nb2 + r; if (row > nN - 1) row = nN - 1;
                int sw = (c16 ^ (r & 15)) << 4;
                char* bptr = dbuf + (it * 16 + wv * 4) * 256;
                gload_lds16(aggP + (size_t)row * 512 + sw, bptr);
                gload_lds16((const char*)hB + (size_t)row * 256 + sw, bptr + 8192);
            }
            #pragma unroll
            for (int it = 0; it < 2; ++it) {
                int pos = it * 512 + lane * 8;
                int node = nb2 + wv * 8 + (pos >> 7);
                if (node > nN - 1) node = nN - 1;
                const float* g = prevh + (size_t)node * DD + (pos & 127);
                p0[it] = *(const f32x4*)g;
                p1[it] = *(const f32x4*)(g + 4);
            }
        }

        const unsigned short* lA = lds + cur * 12288;
        const unsigned short* lH = lA + 4096;
        const unsigned short* lP = lA + 8192;

        f32x4 accM[2][2], accG[2][2];
        #pragma unroll
        for (int mt = 0; mt < 2; ++mt)
            #pragma unroll
            for (int nt = 0; nt < 2; ++nt) {
                accM[mt][nt] = (f32x4){0.f, 0.f, 0.f, 0.f};
                accG[mt][nt] = (f32x4){0.f, 0.f, 0.f, 0.f};
            }
        #pragma unroll
        for (int ks = 0; ks < 4; ++ks) {
            int swz = ((ks * 4 + q) ^ cl) << 3;
            #pragma unroll
            for (int mt = 0; mt < 2; ++mt) {
                int off = (mt * 16 + cl) * 128 + swz;
                short8 aA = *(const short8*)(lA + off);
                short8 aH = *(const short8*)(lH + off);
                short8 aP = *(const short8*)(lP + off);
                #pragma unroll
                for (int nt = 0; nt < 2; ++nt) {
                    accM[mt][nt] = __builtin_amdgcn_mfma_f32_16x16x32_bf16(
                        aA, bn[ks][nt], accM[mt][nt], 0, 0, 0);
                    accM[mt][nt] = __builtin_amdgcn_mfma_f32_16x16x32_bf16(
                        aH, bl[ks][nt], accM[mt][nt], 0, 0, 0);
                    accG[mt][nt] = __builtin_amdgcn_mfma_f32_16x16x32_bf16(
                        aP, bs[ks][nt], accG[mt][nt], 0, 0, 0);
                }
            }
        }

        #pragma unroll
        for (int mt = 0; mt < 2; ++mt) {
            #pragma unroll
            for (int r = 0; r < 4; ++r) {
                int nrow = mt * 16 + q * 4 + r;
                int node = node_base + nrow;
                if (node >= nN) continue;
                #pragma unroll
                for (int nt = 0; nt < 2; ++nt) {
                    int col = ncb + nt * 16 + cl;
                    float pv = bfu(lP[nrow * 128 +
                                      ((((col >> 3) ^ (nrow & 15)) << 3) | (col & 7))]);
                    float sg = 1.0f / (1.0f + __expf(-(accG[mt][nt][r] +
                                                       (nt ? b1 : b0))));
                    float o  = sg * accM[mt][nt][r] + (1.0f - sg) * pv;
                    out[(size_t)node * DD + col] = (o > 0.f ? o : 0.f);
                }
            }
        }

        if (more) {
            char* dbuf = (char*)lds + (cur ^ 1) * 24576;
            #pragma unroll
            for (int it = 0; it < 2; ++it) {
                int pos = it * 512 + lane * 8;
                int r = wv * 8 + (pos >> 7);
                int c = (pos & 127) >> 3;
                short8 p;
                #pragma unroll
                for (int j = 0; j < 4; ++j) {
                    p[j]     = (short)f2bf(p0[it][j]);
                    p[4 + j] = (short)f2bf(p1[it][j]);
                }
                *(short8*)(dbuf + 16384 + r * 256 + ((c ^ (r & 15)) << 4)) = p;
            }
        }
        __syncthreads();
        if (!more) break;
        cur ^= 1;
        t = tn;
    }
}

// ---- patch deg==0 nodes exactly (fp32)
__global__ __launch_bounds__(256) void fix_k(
    const float* __restrict__ h, const float* __restrict__ prevh,
    const float* __restrict__ bias, const float* __restrict__ We,
    const float* __restrict__ Wsk, const int* __restrict__ deg,
    float* __restrict__ out, int nN, int chunk) {
    __shared__ int list[256];
    __shared__ int cnt;
    __shared__ float hrow[DD], prow[DD], res[2][DD];
    int tid = threadIdx.x;
    int base = blockIdx.x * chunk;
    for (int c = base; c < base + chunk && c < nN; c += 256) {
        if (tid == 0) cnt = 0;
        __syncthreads();
        int v = c + tid;
        if (v < nN && v < base + chunk && deg[v] == 0)
            list[atomicAdd(&cnt, 1)] = v;
        __syncthreads();
        int m = cnt;
        for (int i = 0; i < m; ++i) {
            int node = list[i];
            if (tid < DD) hrow[tid] = h[(size_t)node * DD + tid];
            else prow[tid - DD] = prevh[(size_t)node * DD + tid - DD];
            __syncthreads();
            int col = tid & (DD - 1);
            int half = tid >> 7;
            const float* W = half ? Wsk : We;
            const float* x = half ? prow : hrow;
            float s = 0.f;
            for (int k = 0; k < DD; ++k) s += x[k] * W[k * DD + col];
            res[half][col] = s;
            __syncthreads();
            if (tid < DD) {
                float sg = 1.0f / (1.0f + __expf(-(res[1][col] + bias[col])));
                float o  = sg * res[0][col] + (1.0f - sg) * prow[col];
                out[(size_t)node * DD + col] = (o > 0.f ? o : 0.f);
            }
            __syncthreads();
        }
        __syncthreads();
    }
}

extern "C" void kernel_launch(void* const* d_in, const int* in_sizes, int n_in,
                              void* d_out, int out_size, void* d_ws, size_t ws_size,
                              hipStream_t stream) {
    const float* h     = (const float*)d_in[0];
    const float* prevh = (const float*)d_in[1];
    const float* emb   = (const float*)d_in[2];
    const float* normv = (const float*)d_in[3];
    const float* Wn    = (const float*)d_in[4];
    const float* Wl    = (const float*)d_in[5];
    const float* We    = (const float*)d_in[6];
    const float* Wsk   = (const float*)d_in[7];
    const float* bias  = (const float*)d_in[8];
    const int* src   = (const int*)d_in[9];
    const int* dst   = (const int*)d_in[10];
    const int* etype = (const int*)d_in[11];

    int nN = in_sizes[3];       // norm is [N,1]
    int nE = in_sizes[9];
    int nEmbEl = in_sizes[2];   // NUM_RELS * 128

    int nBuck  = (nN + 127) / 128;          // <= 2048 for nN <= 262144
    int nChunk = (nE + SCHUNK - 1) / SCHUNK;

    // ws: Wt | embB | deg | off | bucketBase | bucketTot | chunkHist |
    //     edges u32 | staging u32 | hB
    char* w = (char*)d_ws;
    size_t o = 0;
    unsigned short* Wt = (unsigned short*)(w + o);  o += 3 * DD * DD * 2;
    unsigned short* embB = (unsigned short*)(w + o); o += ((size_t)nEmbEl * 2 + 255) & ~(size_t)255;
    int* deg        = (int*)(w + o);  o += ((size_t)nN * 4 + 15) & ~(size_t)15;
    int* offA       = (int*)(w + o);  o += ((size_t)nN * 4 + 15) & ~(size_t)15;
    int* bucketBase = (int*)(w + o);  o += ((size_t)(nBuck + 1) * 4 + 15) & ~(size_t)15;
    int* bucketTot  = (int*)(w + o);  o += ((size_t)nBuck * 4 + 15) & ~(size_t)15;
    int* chunkHist  = (int*)(w + o);  o += ((size_t)nChunk * nBuck * 4 + 15) & ~(size_t)15;
    unsigned int* edges   = (unsigned int*)(w + o); o += ((size_t)nE * 4 + 15) & ~(size_t)15;
    unsigned int* staging = (unsigned int*)(w + o); o += ((size_t)nE * 4 + 15) & ~(size_t)15;
    unsigned short* hB = (unsigned short*)(w + o);

    int totalH = nN * DD;
    int nConvH = (totalH + 8191) / 8192;
    int nEmbB  = (nEmbEl + 2047) / 2048;
    int nTiles = (nN + 31) / 32;
    int fgrid2 = nTiles < 512 ? nTiles : 512;

    prep_k<<<nChunk + nConvH + 48 + nEmbB, 256, 0, stream>>>(
        h, Wn, Wl, Wsk, emb, dst, hB, embB, Wt, chunkHist,
        nN, nEmbEl, nE, nBuck, nChunk);
    scanB1_k<<<(nBuck + 255) / 256, 256, 0, stream>>>(chunkHist, bucketTot,
                                                      nBuck, nChunk);
    scanB2_k<<<1, 1024, 0, stream>>>(bucketTot, bucketBase, nBuck, nE);
    sort1_k<<<nChunk, 256, 0, stream>>>(src, dst, etype, nE, nBuck,
                                        chunkHist, bucketBase, staging);
    sort2_k<<<nBuck, 256, 0, stream>>>(staging, bucketBase, nN, edges, offA, deg);
    gather_k<<<(nN + 15) / 16, 256, 0, stream>>>(hB, embB, edges, offA, deg, normv,
                                                 (char*)d_out, nN);
    fused_k<<<fgrid2, 256, 49152, stream>>>(hB, prevh, bias, (const char*)d_out,
                                            Wt, (float*)d_out, nN, nTiles);
    int fgrid = 256;
    int chunk = ((nN + fgrid * 256 - 1) / (fgrid * 256)) * 256;
    fix_k<<<fgrid, 256, 0, stream>>>(h, prevh, bias, We, Wsk, deg, (float*)d_out,
                                     nN, chunk);
    (void)ws_size; (void)n_in; (void)out_size;
}

// Round 8
// 267.959 us; speedup vs baseline: 1.1233x; 1.1233x over previous
//
#include <hip/hip_runtime.h>

#define DD 128
#define SCHUNK 4096

typedef __attribute__((ext_vector_type(8))) short short8;
typedef __attribute__((ext_vector_type(4))) float f32x4;
typedef __attribute__((ext_vector_type(2))) float f32x2;
typedef __attribute__((ext_vector_type(4))) int i32x4;
typedef __attribute__((ext_vector_type(4))) unsigned int u32x4;

__device__ __forceinline__ unsigned short f2bf(float f) {
    union { float f; unsigned int i; } c; c.f = f;
    unsigned int x = c.i;
    return (unsigned short)((x + 0x7fffu + ((x >> 16) & 1u)) >> 16);
}
__device__ __forceinline__ float bfu(unsigned short u) {
    union { unsigned int i; float f; } c; c.i = ((unsigned int)u) << 16; return c.f;
}
// unpack u32 of 2 bf16 -> {lo, hi} f32 pair (2 VALU ops, feeds v_pk_add_f32)
__device__ __forceinline__ f32x2 bf2lohi(unsigned int w) {
    union { unsigned int i; float f; } lo, hi;
    lo.i = w << 16;
    hi.i = w & 0xFFFF0000u;
    return (f32x2){lo.f, hi.f};
}
// async 16B global -> LDS (dest is wave-uniform base + lane*16)
__device__ __forceinline__ void gload_lds16(const void* g, void* l) {
    __builtin_amdgcn_global_load_lds(
        (const __attribute__((address_space(1))) unsigned int*)g,
        (__attribute__((address_space(3))) unsigned int*)l, 16, 0, 0);
}
// Index accessor robust to int32 vs int64 (little-endian, nonneg values < 2^31)
__device__ __forceinline__ int idx_at(const int* p, int e, int is64) {
    return is64 ? p[2 * e] : p[e];
}
// Per-block int64 detection: int64 => odd 32-bit words (high halves) all zero.
__device__ __forceinline__ int block_is64(const int* dst, int nE, int* s_flag) {
    if (threadIdx.x == 0) *s_flag = 0;
    __syncthreads();
    int w = 2 * (int)threadIdx.x + 1;
    if (threadIdx.x < 128 && w < nE && dst[w] != 0) atomicOr(s_flag, 1);
    __syncthreads();
    return !*s_flag;
}

// ---- prep: one kernel, roles by blockIdx:
// [0, nChunk)   : per-chunk coarse-bucket histogram (dst>>7), LDS-privatized,
//                 dense coalesced row write to chunkHist[c][b] -- NO global
//                 atomics
// [+nConvH)     : h fp32 -> hB bf16, 8192 elems/block, 8 loads in flight
// [+48)         : 3 weights transposed+converted into Wt
// [+nEmbB)      : emb fp32 -> embB bf16
__global__ __launch_bounds__(256) void prep_k(
    const float* __restrict__ h,
    const float* __restrict__ W0, const float* __restrict__ W1,
    const float* __restrict__ W2, const float* __restrict__ emb,
    const int* __restrict__ dst,
    unsigned short* __restrict__ hB,
    unsigned short* __restrict__ embB, unsigned short* __restrict__ Wt,
    int* __restrict__ chunkHist, int nN, int nEmbEl, int nE,
    int nBuck, int nChunk) {
    int tid = threadIdx.x;
    int bid = blockIdx.x;
    if (bid < nChunk) {
        __shared__ int hist[2048];
        __shared__ int s_flag;
        int is64 = block_is64(dst, nE, &s_flag);
        for (int i = tid; i < nBuck; i += 256) hist[i] = 0;
        __syncthreads();
        int cbase = bid * SCHUNK;
        #pragma unroll
        for (int j = 0; j < SCHUNK / 256; ++j) {
            int e = cbase + j * 256 + tid;
            if (e < nE) atomicAdd(&hist[idx_at(dst, e, is64) >> 7], 1);
        }
        __syncthreads();
        for (int b = tid; b < nBuck; b += 256)
            chunkHist[bid * nBuck + b] = hist[b];
        return;
    }
    bid -= nChunk;
    int totalH = nN * DD;
    int nConvH = (totalH + 8191) / 8192;
    if (bid < nConvH) {
        int base0 = bid * 8192;
        if (base0 + 8192 <= totalH) {
            int base = base0 + tid * 8;
            f32x4 x[4][2];
            #pragma unroll
            for (int i = 0; i < 4; ++i) {
                x[i][0] = *(const f32x4*)(h + base + i * 2048);
                x[i][1] = *(const f32x4*)(h + base + i * 2048 + 4);
            }
            #pragma unroll
            for (int i = 0; i < 4; ++i) {
                short8 p;
                #pragma unroll
                for (int j = 0; j < 4; ++j) {
                    p[j]     = (short)f2bf(x[i][0][j]);
                    p[4 + j] = (short)f2bf(x[i][1][j]);
                }
                *(short8*)(hB + base + i * 2048) = p;
            }
        } else {
            #pragma unroll
            for (int i = 0; i < 4; ++i) {
                int b2 = base0 + i * 2048 + tid * 8;
                if (b2 + 8 <= totalH) {
                    f32x4 x0 = *(const f32x4*)(h + b2);
                    f32x4 x1 = *(const f32x4*)(h + b2 + 4);
                    short8 p;
                    #pragma unroll
                    for (int j = 0; j < 4; ++j) {
                        p[j]     = (short)f2bf(x0[j]);
                        p[4 + j] = (short)f2bf(x1[j]);
                    }
                    *(short8*)(hB + b2) = p;
                } else {
                    for (int j = b2; j < totalH && j < b2 + 8; ++j)
                        hB[j] = f2bf(h[j]);
                }
            }
        }
        return;
    }
    bid -= nConvH;
    if (bid < 48) {
        const float* Ws[3] = {W0, W1, W2};
        int w = bid >> 4, chunk = bid & 15;
        unsigned short* T = Wt + w * (DD * DD);
        #pragma unroll
        for (int i = 0; i < 4; ++i) {
            int t = chunk * 1024 + i * 256 + tid;
            int n = t >> 7, k = t & 127;
            T[t] = f2bf(Ws[w][k * DD + n]);
        }
        return;
    }
    bid -= 48;
    // emb role
    int base = bid * 2048 + tid * 8;
    if (base + 8 <= nEmbEl) {
        f32x4 x0 = *(const f32x4*)(emb + base);
        f32x4 x1 = *(const f32x4*)(emb + base + 4);
        short8 p;
        #pragma unroll
        for (int j = 0; j < 4; ++j) {
            p[j]     = (short)f2bf(x0[j]);
            p[4 + j] = (short)f2bf(x1[j]);
        }
        *(short8*)(embB + base) = p;
    } else {
        for (int j = base; j < nEmbEl; ++j) embB[j] = f2bf(emb[j]);
    }
}

// ---- column-scan of chunkHist (per bucket, over chunks), in place:
// WAVE-PARALLEL over the chunk dimension (round-7 version was thread-serial:
// 13 waves on the whole GPU x 147 dependent L2 round-trips = ~18us latency
// chain). One wave per bucket, lanes = chunks, 6-step shfl_up inclusive scan,
// carry across 64-chunk strips. 782 waves -> fully latency-hidden.
__global__ __launch_bounds__(256) void scanB1_k(int* __restrict__ chunkHist,
                                                int* __restrict__ bucketTot,
                                                int nBuck, int nChunk) {
    int lane = threadIdx.x & 63;
    int b = blockIdx.x * 4 + (threadIdx.x >> 6);   // one wave per bucket
    if (b >= nBuck) return;
    int tot = 0;
    for (int cs = 0; cs < nChunk; cs += 64) {
        int c = cs + lane;
        int v = (c < nChunk) ? chunkHist[(size_t)c * nBuck + b] : 0;
        int s = v;
        #pragma unroll
        for (int d = 1; d < 64; d <<= 1) {
            int x = __shfl_up(s, d);
            if (lane >= d) s += x;
        }
        if (c < nChunk) chunkHist[(size_t)c * nBuck + b] = s - v + tot;
        tot += __shfl(s, 63);
    }
    if (lane == 0) bucketTot[b] = tot;
}

// ---- exclusive scan of bucket totals -> bucketBase (one block, 2 slots/thread,
// supports nBuck <= 2048); bucketBase[nBuck] = nE.
__global__ __launch_bounds__(1024) void scanB2_k(const int* __restrict__ bucketTot,
                                                 int* __restrict__ bucketBase,
                                                 int nBuck, int nE) {
    __shared__ int s[2048];
    int t = threadIdx.x;
    int b0 = t, b1 = t + 1024;
    int v0 = (b0 < nBuck) ? bucketTot[b0] : 0;
    int v1 = (b1 < nBuck) ? bucketTot[b1] : 0;
    s[b0] = v0;
    s[b1] = v1;
    __syncthreads();
    for (int d = 1; d < 2048; d <<= 1) {
        int x0 = (b0 >= d) ? s[b0 - d] : 0;
        int x1 = (b1 >= d) ? s[b1 - d] : 0;
        __syncthreads();
        s[b0] += x0;
        s[b1] += x1;
        __syncthreads();
    }
    if (b0 < nBuck) bucketBase[b0] = s[b0] - v0;
    if (b1 < nBuck) bucketBase[b1] = s[b1] - v1;
    if (t == 0) bucketBase[nBuck] = nE;
}

// ---- sort phase 1: partition edges into coarse buckets (dst>>7); run base is
// bucketBase[b] + chunkHist[c][b] -- fully deterministic, zero global atomics.
// staged word = src | et<<17 | (dst&127)<<25.
__global__ __launch_bounds__(256) void sort1_k(
    const int* __restrict__ src, const int* __restrict__ dst,
    const int* __restrict__ et, int nE, int nBuck,
    const int* __restrict__ chunkHist, const int* __restrict__ bucketBase,
    unsigned int* __restrict__ staging) {
    __shared__ int hist[2048];
    __shared__ int rbase[2048];
    __shared__ unsigned short ranks[SCHUNK];
    __shared__ int s_flag;
    int tid = threadIdx.x;
    int is64 = block_is64(dst, nE, &s_flag);
    for (int i = tid; i < nBuck; i += 256) hist[i] = 0;
    __syncthreads();
    int c = blockIdx.x;
    int cbase = c * SCHUNK;
    #pragma unroll
    for (int j = 0; j < SCHUNK / 256; ++j) {
        int e = cbase + j * 256 + tid;
        if (e < nE) {
            int d = idx_at(dst, e, is64);
            ranks[j * 256 + tid] = (unsigned short)atomicAdd(&hist[d >> 7], 1);
        }
    }
    __syncthreads();
    for (int b = tid; b < nBuck; b += 256)
        rbase[b] = bucketBase[b] + chunkHist[c * nBuck + b];
    __syncthreads();
    #pragma unroll
    for (int j = 0; j < SCHUNK / 256; ++j) {
        int e = cbase + j * 256 + tid;
        if (e < nE) {
            int d = idx_at(dst, e, is64);
            unsigned int wd = (unsigned int)idx_at(src, e, is64) |
                              ((unsigned int)idx_at(et, e, is64) << 17) |
                              ((unsigned int)(d & 127) << 25);
            staging[rbase[d >> 7] + (int)ranks[j * 256 + tid]] = wd;
        }
    }
}

// ---- sort phase 2: one block per bucket. Counts per-node in LDS, 128-wide
// exclusive scan -> derives off[v] and deg[v] (coalesced writes), then
// scatters edges within the bucket's contiguous, L2-hot region.
__global__ __launch_bounds__(256) void sort2_k(
    const unsigned int* __restrict__ staging, const int* __restrict__ bucketBase,
    int nN, unsigned int* __restrict__ edges,
    int* __restrict__ off, int* __restrict__ deg) {
    __shared__ int cnt[128];
    __shared__ int sc[128];
    __shared__ int cur[128];
    int b = blockIdx.x;
    int first = b << 7;
    int tid = threadIdx.x;
    if (tid < 128) cnt[tid] = 0;
    int rStart = bucketBase[b];
    int rEnd = bucketBase[b + 1];
    __syncthreads();
    for (int i = rStart + tid; i < rEnd; i += 256)
        atomicAdd(&cnt[staging[i] >> 25], 1);
    __syncthreads();
    if (tid < 128) sc[tid] = cnt[tid];
    __syncthreads();
    for (int d = 1; d < 128; d <<= 1) {
        int x = 0;
        if (tid < 128 && tid >= d) x = sc[tid - d];
        __syncthreads();
        if (tid < 128) sc[tid] += x;
        __syncthreads();
    }
    if (tid < 128) {
        int o = rStart + sc[tid] - cnt[tid];
        cur[tid] = o;
        int v = first + tid;
        if (v < nN) { off[v] = o; deg[v] = cnt[tid]; }
    }
    __syncthreads();
    for (int i = rStart + tid; i < rEnd; i += 256) {
        unsigned int wd = staging[i];
        int p = atomicAdd(&cur[wd >> 25], 1);
        edges[p] = wd & 0x1FFFFFFu;
    }
}

// ---- CSR gather, node-per-16-lane-group: 4 nodes per wave, 16 nodes per
// block. Channels lane-local, no cross-lane reduce; f32x2 accumulators
// (v_pk_add_f32), v_cvt_pk_bf16_f32 pack epilogue.
__global__ __launch_bounds__(256) void gather_k(
    const unsigned short* __restrict__ hB, const unsigned short* __restrict__ embB,
    const unsigned int* __restrict__ edges, const int* __restrict__ off,
    const int* __restrict__ deg, const float* __restrict__ normv,
    char* __restrict__ aggP, int nN) {
    int lane = threadIdx.x & 63;
    int l16 = lane & 15;
    int v = blockIdx.x * 16 + ((threadIdx.x >> 6) << 2) + (lane >> 4);
    if (v >= nN) return;
    int b = off[v], n = deg[v];
    f32x2 a2[4] = {{0.f, 0.f}, {0.f, 0.f}, {0.f, 0.f}, {0.f, 0.f}};
    for (int m = 0; m < n; m += 2) {
        bool e1 = (m + 1) < n;
        unsigned int w0 = edges[b + m];
        unsigned int w1 = e1 ? edges[b + m + 1] : 0u;
        short8 h0 = *(const short8*)(hB + (size_t)(w0 & 0x1FFFFu) * DD + l16 * 8);
        short8 r0 = *(const short8*)(embB + (size_t)(w0 >> 17) * DD + l16 * 8);
        short8 h1, r1;
        if (e1) {
            h1 = *(const short8*)(hB + (size_t)(w1 & 0x1FFFFu) * DD + l16 * 8);
            r1 = *(const short8*)(embB + (size_t)(w1 >> 17) * DD + l16 * 8);
        }
        union { short8 s; u32x4 u; } ch0, cr0;
        ch0.s = h0; cr0.s = r0;
        #pragma unroll
        for (int k = 0; k < 4; ++k) {
            a2[k] += bf2lohi(ch0.u[k]);
            a2[k] += bf2lohi(cr0.u[k]);
        }
        if (e1) {
            union { short8 s; u32x4 u; } ch1, cr1;
            ch1.s = h1; cr1.s = r1;
            #pragma unroll
            for (int k = 0; k < 4; ++k) {
                a2[k] += bf2lohi(ch1.u[k]);
                a2[k] += bf2lohi(cr1.u[k]);
            }
        }
    }
    float nm = normv[v];
    unsigned int pk[4];
    #pragma unroll
    for (int k = 0; k < 4; ++k) {
        float x0 = a2[k][0] * nm, x1 = a2[k][1] * nm;
        asm("v_cvt_pk_bf16_f32 %0, %1, %2" : "=v"(pk[k]) : "v"(x0), "v"(x1));
    }
    i32x4 w;
    w[0] = (int)pk[0]; w[1] = (int)pk[1]; w[2] = (int)pk[2]; w[3] = (int)pk[3];
    *(i32x4*)(aggP + (size_t)v * 512 + l16 * 16) = w;
}

// ---- fused 3-GEMM + epilogue: persistent double-buffered pipeline,
// 32-node tiles, 48KB dynamic LDS -> 2 blocks/CU. Wt fragments hoisted.
// deg==0 rows patched exactly by fix_k afterwards.
__global__ __launch_bounds__(256, 2) void fused_k(
    const unsigned short* __restrict__ hB,
    const float* __restrict__ prevh,
    const float* __restrict__ bias,
    const char* __restrict__ aggP,       // = d_out: [0,256) of each 512B slot = agg bf16
    const unsigned short* __restrict__ Wt,
    float* __restrict__ out, int nN, int nTiles) {
    extern __shared__ unsigned short lds[];   // 2 * 12288 u16 = 48KB
    const int lane = threadIdx.x & 63;
    const int wv = threadIdx.x >> 6;
    const int q = lane >> 4, cl = lane & 15;
    const int ncb = wv * 32;
    const int stride = gridDim.x;

    int t = blockIdx.x;
    if (t >= nTiles) return;

    short8 bn[4][2], bl[4][2], bs[4][2];
    #pragma unroll
    for (int ks = 0; ks < 4; ++ks)
        #pragma unroll
        for (int nt = 0; nt < 2; ++nt) {
            int n = (ncb + nt * 16 + cl) * DD + ks * 32 + q * 8;
            bn[ks][nt] = *(const short8*)(Wt + n);
            bl[ks][nt] = *(const short8*)(Wt + DD * DD + n);
            bs[ks][nt] = *(const short8*)(Wt + 2 * DD * DD + n);
        }
    const float b0 = bias[ncb + cl], b1 = bias[ncb + 16 + cl];

    const int r0 = lane >> 4;
    const int c16 = lane & 15;

    {
        int node_base = t * 32;
        #pragma unroll
        for (int it = 0; it < 2; ++it) {
            int r = it * 16 + wv * 4 + r0;
            int row = node_base + r; if (row > nN - 1) row = nN - 1;
            int sw = (c16 ^ (r & 15)) << 4;
            char* bptr = (char*)lds + (it * 16 + wv * 4) * 256;
            gload_lds16(aggP + (size_t)row * 512 + sw, bptr);
            gload_lds16((const char*)hB + (size_t)row * 256 + sw, bptr + 8192);
        }
        f32x4 p0[2], p1[2];
        #pragma unroll
        for (int it = 0; it < 2; ++it) {
            int pos = it * 512 + lane * 8;
            int node = node_base + wv * 8 + (pos >> 7);
            if (node > nN - 1) node = nN - 1;
            const float* g = prevh + (size_t)node * DD + (pos & 127);
            p0[it] = *(const f32x4*)g;
            p1[it] = *(const f32x4*)(g + 4);
        }
        #pragma unroll
        for (int it = 0; it < 2; ++it) {
            int pos = it * 512 + lane * 8;
            int r = wv * 8 + (pos >> 7);
            int c = (pos & 127) >> 3;
            short8 p;
            #pragma unroll
            for (int j = 0; j < 4; ++j) {
                p[j]     = (short)f2bf(p0[it][j]);
                p[4 + j] = (short)f2bf(p1[it][j]);
            }
            *(short8*)((char*)lds + 16384 + r * 256 + ((c ^ (r & 15)) << 4)) = p;
        }
    }
    __syncthreads();

    int cur = 0;
    for (;;) {
        int node_base = t * 32;
        int tn = t + stride;
        bool more = (tn < nTiles);

        f32x4 p0[2], p1[2];
        if (more) {
            int nb2 = tn * 32;
            char* dbuf = (char*)lds + (cur ^ 1) * 24576;
            #pragma unroll
            for (int it = 0; it < 2; ++it) {
                int r = it * 16 + wv * 4 + r0;
                int row = nb2 + r; if (row > nN - 1) row = nN - 1;
                int sw = (c16 ^ (r & 15)) << 4;
                char* bptr = dbuf + (it * 16 + wv * 4) * 256;
                gload_lds16(aggP + (size_t)row * 512 + sw, bptr);
                gload_lds16((const char*)hB + (size_t)row * 256 + sw, bptr + 8192);
            }
            #pragma unroll
            for (int it = 0; it < 2; ++it) {
                int pos = it * 512 + lane * 8;
                int node = nb2 + wv * 8 + (pos >> 7);
                if (node > nN - 1) node = nN - 1;
                const float* g = prevh + (size_t)node * DD + (pos & 127);
                p0[it] = *(const f32x4*)g;
                p1[it] = *(const f32x4*)(g + 4);
            }
        }

        const unsigned short* lA = lds + cur * 12288;
        const unsigned short* lH = lA + 4096;
        const unsigned short* lP = lA + 8192;

        f32x4 accM[2][2], accG[2][2];
        #pragma unroll
        for (int mt = 0; mt < 2; ++mt)
            #pragma unroll
            for (int nt = 0; nt < 2; ++nt) {
                accM[mt][nt] = (f32x4){0.f, 0.f, 0.f, 0.f};
                accG[mt][nt] = (f32x4){0.f, 0.f, 0.f, 0.f};
            }
        #pragma unroll
        for (int ks = 0; ks < 4; ++ks) {
            int swz = ((ks * 4 + q) ^ cl) << 3;
            #pragma unroll
            for (int mt = 0; mt < 2; ++mt) {
                int off = (mt * 16 + cl) * 128 + swz;
                short8 aA = *(const short8*)(lA + off);
                short8 aH = *(const short8*)(lH + off);
                short8 aP = *(const short8*)(lP + off);
                #pragma unroll
                for (int nt = 0; nt < 2; ++nt) {
                    accM[mt][nt] = __builtin_amdgcn_mfma_f32_16x16x32_bf16(
                        aA, bn[ks][nt], accM[mt][nt], 0, 0, 0);
                    accM[mt][nt] = __builtin_amdgcn_mfma_f32_16x16x32_bf16(
                        aH, bl[ks][nt], accM[mt][nt], 0, 0, 0);
                    accG[mt][nt] = __builtin_amdgcn_mfma_f32_16x16x32_bf16(
                        aP, bs[ks][nt], accG[mt][nt], 0, 0, 0);
                }
            }
        }

        #pragma unroll
        for (int mt = 0; mt < 2; ++mt) {
            #pragma unroll
            for (int r = 0; r < 4; ++r) {
                int nrow = mt * 16 + q * 4 + r;
                int node = node_base + nrow;
                if (node >= nN) continue;
                #pragma unroll
                for (int nt = 0; nt < 2; ++nt) {
                    int col = ncb + nt * 16 + cl;
                    float pv = bfu(lP[nrow * 128 +
                                      ((((col >> 3) ^ (nrow & 15)) << 3) | (col & 7))]);
                    float sg = 1.0f / (1.0f + __expf(-(accG[mt][nt][r] +
                                                       (nt ? b1 : b0))));
                    float o  = sg * accM[mt][nt][r] + (1.0f - sg) * pv;
                    out[(size_t)node * DD + col] = (o > 0.f ? o : 0.f);
                }
            }
        }

        if (more) {
            char* dbuf = (char*)lds + (cur ^ 1) * 24576;
            #pragma unroll
            for (int it = 0; it < 2; ++it) {
                int pos = it * 512 + lane * 8;
                int r = wv * 8 + (pos >> 7);
                int c = (pos & 127) >> 3;
                short8 p;
                #pragma unroll
                for (int j = 0; j < 4; ++j) {
                    p[j]     = (short)f2bf(p0[it][j]);
                    p[4 + j] = (short)f2bf(p1[it][j]);
                }
                *(short8*)(dbuf + 16384 + r * 256 + ((c ^ (r & 15)) << 4)) = p;
            }
        }
        __syncthreads();
        if (!more) break;
        cur ^= 1;
        t = tn;
    }
}

// ---- patch deg==0 nodes exactly (fp32)
__global__ __launch_bounds__(256) void fix_k(
    const float* __restrict__ h, const float* __restrict__ prevh,
    const float* __restrict__ bias, const float* __restrict__ We,
    const float* __restrict__ Wsk, const int* __restrict__ deg,
    float* __restrict__ out, int nN, int chunk) {
    __shared__ int list[256];
    __shared__ int cnt;
    __shared__ float hrow[DD], prow[DD], res[2][DD];
    int tid = threadIdx.x;
    int base = blockIdx.x * chunk;
    for (int c = base; c < base + chunk && c < nN; c += 256) {
        if (tid == 0) cnt = 0;
        __syncthreads();
        int v = c + tid;
        if (v < nN && v < base + chunk && deg[v] == 0)
            list[atomicAdd(&cnt, 1)] = v;
        __syncthreads();
        int m = cnt;
        for (int i = 0; i < m; ++i) {
            int node = list[i];
            if (tid < DD) hrow[tid] = h[(size_t)node * DD + tid];
            else prow[tid - DD] = prevh[(size_t)node * DD + tid - DD];
            __syncthreads();
            int col = tid & (DD - 1);
            int half = tid >> 7;
            const float* W = half ? Wsk : We;
            const float* x = half ? prow : hrow;
            float s = 0.f;
            for (int k = 0; k < DD; ++k) s += x[k] * W[k * DD + col];
            res[half][col] = s;
            __syncthreads();
            if (tid < DD) {
                float sg = 1.0f / (1.0f + __expf(-(res[1][col] + bias[col])));
                float o  = sg * res[0][col] + (1.0f - sg) * prow[col];
                out[(size_t)node * DD + col] = (o > 0.f ? o : 0.f);
            }
            __syncthreads();
        }
        __syncthreads();
    }
}

extern "C" void kernel_launch(void* const* d_in, const int* in_sizes, int n_in,
                              void* d_out, int out_size, void* d_ws, size_t ws_size,
                              hipStream_t stream) {
    const float* h     = (const float*)d_in[0];
    const float* prevh = (const float*)d_in[1];
    const float* emb   = (const float*)d_in[2];
    const float* normv = (const float*)d_in[3];
    const float* Wn    = (const float*)d_in[4];
    const float* Wl    = (const float*)d_in[5];
    const float* We    = (const float*)d_in[6];
    const float* Wsk   = (const float*)d_in[7];
    const float* bias  = (const float*)d_in[8];
    const int* src   = (const int*)d_in[9];
    const int* dst   = (const int*)d_in[10];
    const int* etype = (const int*)d_in[11];

    int nN = in_sizes[3];       // norm is [N,1]
    int nE = in_sizes[9];
    int nEmbEl = in_sizes[2];   // NUM_RELS * 128

    int nBuck  = (nN + 127) / 128;          // <= 2048 for nN <= 262144
    int nChunk = (nE + SCHUNK - 1) / SCHUNK;

    // ws: Wt | embB | deg | off | bucketBase | bucketTot | chunkHist |
    //     edges u32 | staging u32 | hB
    char* w = (char*)d_ws;
    size_t o = 0;
    unsigned short* Wt = (unsigned short*)(w + o);  o += 3 * DD * DD * 2;
    unsigned short* embB = (unsigned short*)(w + o); o += ((size_t)nEmbEl * 2 + 255) & ~(size_t)255;
    int* deg        = (int*)(w + o);  o += ((size_t)nN * 4 + 15) & ~(size_t)15;
    int* offA       = (int*)(w + o);  o += ((size_t)nN * 4 + 15) & ~(size_t)15;
    int* bucketBase = (int*)(w + o);  o += ((size_t)(nBuck + 1) * 4 + 15) & ~(size_t)15;
    int* bucketTot  = (int*)(w + o);  o += ((size_t)nBuck * 4 + 15) & ~(size_t)15;
    int* chunkHist  = (int*)(w + o);  o += ((size_t)nChunk * nBuck * 4 + 15) & ~(size_t)15;
    unsigned int* edges   = (unsigned int*)(w + o); o += ((size_t)nE * 4 + 15) & ~(size_t)15;
    unsigned int* staging = (unsigned int*)(w + o); o += ((size_t)nE * 4 + 15) & ~(size_t)15;
    unsigned short* hB = (unsigned short*)(w + o);

    int totalH = nN * DD;
    int nConvH = (totalH + 8191) / 8192;
    int nEmbB  = (nEmbEl + 2047) / 2048;
    int nTiles = (nN + 31) / 32;
    int fgrid2 = nTiles < 512 ? nTiles : 512;

    prep_k<<<nChunk + nConvH + 48 + nEmbB, 256, 0, stream>>>(
        h, Wn, Wl, Wsk, emb, dst, hB, embB, Wt, chunkHist,
        nN, nEmbEl, nE, nBuck, nChunk);
    scanB1_k<<<(nBuck + 3) / 4, 256, 0, stream>>>(chunkHist, bucketTot,
                                                  nBuck, nChunk);
    scanB2_k<<<1, 1024, 0, stream>>>(bucketTot, bucketBase, nBuck, nE);
    sort1_k<<<nChunk, 256, 0, stream>>>(src, dst, etype, nE, nBuck,
                                        chunkHist, bucketBase, staging);
    sort2_k<<<nBuck, 256, 0, stream>>>(staging, bucketBase, nN, edges, offA, deg);
    gather_k<<<(nN + 15) / 16, 256, 0, stream>>>(hB, embB, edges, offA, deg, normv,
                                                 (char*)d_out, nN);
    fused_k<<<fgrid2, 256, 49152, stream>>>(hB, prevh, bias, (const char*)d_out,
                                            Wt, (float*)d_out, nN, nTiles);
    int fgrid = 256;
    int chunk = ((nN + fgrid * 256 - 1) / (fgrid * 256)) * 256;
    fix_k<<<fgrid, 256, 0, stream>>>(h, prevh, bias, We, Wsk, deg, (float*)d_out,
                                     nN, chunk);
    (void)ws_size; (void)n_in; (void)out_size;
}